// Round 2
// baseline (1408.759 us; speedup 1.0000x reference)
//
#include <hip/hip_runtime.h>
#include <math.h>

// Problem constants (from reference): B=128, D=3*32*32=3072, N=50000, NC=10
#define D  3072
#define BQ 128   // query tile = all queries
#define BS 64    // samples per block
#define KC 32    // k-chunk staged in LDS
#define NC 10

// ---------------------------------------------------------------------------
// Kernel 1: per-query ||x||^2  +  init per-query packed argmin to ~0ull
// grid = B blocks x 64 threads (one wave per query row)
// ---------------------------------------------------------------------------
__global__ __launch_bounds__(64) void init_kernel(const float* __restrict__ x,
                                                  float* __restrict__ x2g,
                                                  unsigned long long* __restrict__ gmin) {
    const int b = blockIdx.x;
    const int lane = threadIdx.x;
    const float4* xr = (const float4*)(x + (size_t)b * D);
    float v = 0.f;
#pragma unroll
    for (int i = 0; i < D / 4 / 64; ++i) {   // 12 iters
        float4 t = xr[lane + i * 64];
        v += t.x * t.x + t.y * t.y + t.z * t.z + t.w * t.w;
    }
#pragma unroll
    for (int off = 32; off > 0; off >>= 1) v += __shfl_down(v, off, 64);
    if (lane == 0) {
        x2g[b] = v;
        gmin[b] = ~0ull;
    }
}

// ---------------------------------------------------------------------------
// Kernel 2: fp32 tiled distance + per-query blockwise min + global atomicMin
// grid = ceil(N/BS) blocks x 256 threads.
// Block owns samples [nbase, nbase+BS) for ALL K -> accumulates exact s2
// during staging. Thread layout: tq = tid&15 (8 queries), ts = tid>>4 (4
// samples) -> 8x4 fp32 accumulator micro-tile.
// ---------------------------------------------------------------------------
__global__ __launch_bounds__(256) void dist_kernel(const float* __restrict__ x,
                                                   const float* __restrict__ s,
                                                   const float* __restrict__ x2g,
                                                   unsigned long long* __restrict__ gmin,
                                                   int N) {
    __shared__ float xs[KC][BQ + 4];           // [k][q]  16.9 KB
    __shared__ float ss[KC][BS + 4];           // [k][n]   8.7 KB
    __shared__ float s2part[BS][8];            //          2.0 KB
    __shared__ float s2loc[BS];
    __shared__ float x2s[BQ];
    __shared__ unsigned long long qmin[BQ][16]; //        16.4 KB

    const int tid = threadIdx.x;
    const int tq  = tid & 15;   // query group: rows tq*8 .. tq*8+7
    const int ts  = tid >> 4;   // sample group: cols ts*4 .. ts*4+3
    const int nbase = blockIdx.x * BS;

    if (tid < BQ) x2s[tid] = x2g[tid];

    float acc[8][4];
#pragma unroll
    for (int i = 0; i < 8; ++i)
#pragma unroll
        for (int j = 0; j < 4; ++j) acc[i][j] = 0.f;

    // staging maps: flat f = tid + i*256 ; row = f>>3 ; c4 = f&7 (constant)
    const int c4    = tid & 7;
    const int xrow0 = tid >> 3;        // + i*32, i=0..3 -> rows 0..127
    const int srow0 = tid >> 3;        // 0..31
    const int srow1 = srow0 + 32;      // 32..63
    float s2a = 0.f, s2b = 0.f;
    const int gs0 = min(nbase + srow0, N - 1);   // clamp OOB rows (excluded later)
    const int gs1 = min(nbase + srow1, N - 1);

    for (int k0 = 0; k0 < D; k0 += KC) {
        __syncthreads();
        // ---- stage x tile (128 x 32) ----
#pragma unroll
        for (int i = 0; i < 4; ++i) {
            const int r = xrow0 + i * 32;
            float4 t = *(const float4*)(x + (size_t)r * D + k0 + c4 * 4);
            xs[c4 * 4 + 0][r] = t.x;
            xs[c4 * 4 + 1][r] = t.y;
            xs[c4 * 4 + 2][r] = t.z;
            xs[c4 * 4 + 3][r] = t.w;
        }
        // ---- stage s tile (64 x 32) + s2 partials ----
        {
            float4 t0 = *(const float4*)(s + (size_t)gs0 * D + k0 + c4 * 4);
            float4 t1 = *(const float4*)(s + (size_t)gs1 * D + k0 + c4 * 4);
            ss[c4 * 4 + 0][srow0] = t0.x;
            ss[c4 * 4 + 1][srow0] = t0.y;
            ss[c4 * 4 + 2][srow0] = t0.z;
            ss[c4 * 4 + 3][srow0] = t0.w;
            ss[c4 * 4 + 0][srow1] = t1.x;
            ss[c4 * 4 + 1][srow1] = t1.y;
            ss[c4 * 4 + 2][srow1] = t1.z;
            ss[c4 * 4 + 3][srow1] = t1.w;
            s2a += t0.x * t0.x + t0.y * t0.y + t0.z * t0.z + t0.w * t0.w;
            s2b += t1.x * t1.x + t1.y * t1.y + t1.z * t1.z + t1.w * t1.w;
        }
        __syncthreads();
        // ---- compute: 32 FMA per k per thread ----
#pragma unroll
        for (int k = 0; k < KC; ++k) {
            float4 a0 = *(const float4*)&xs[k][tq * 8];
            float4 a1 = *(const float4*)&xs[k][tq * 8 + 4];
            float4 b0 = *(const float4*)&ss[k][ts * 4];
            const float xa[8] = {a0.x, a0.y, a0.z, a0.w, a1.x, a1.y, a1.z, a1.w};
            const float sb[4] = {b0.x, b0.y, b0.z, b0.w};
#pragma unroll
            for (int i = 0; i < 8; ++i)
#pragma unroll
                for (int j = 0; j < 4; ++j)
                    acc[i][j] = fmaf(xa[i], sb[j], acc[i][j]);
        }
    }

    // ---- reduce s2 partials: 8 per row ----
    s2part[srow0][c4] = s2a;
    s2part[srow1][c4] = s2b;
    __syncthreads();
    if (tid < BS) {
        float t = 0.f;
#pragma unroll
        for (int j = 0; j < 8; ++j) t += s2part[tid][j];
        s2loc[tid] = t;
    }
    __syncthreads();

    // ---- per-thread d2, packed (bits(d2)<<32 | n), min over the 4 samples ----
#pragma unroll
    for (int i = 0; i < 8; ++i) {
        unsigned long long m = ~0ull;
#pragma unroll
        for (int j = 0; j < 4; ++j) {
            const int n = nbase + ts * 4 + j;
            if (n < N) {
                float d2 = x2s[tq * 8 + i] + s2loc[ts * 4 + j] - 2.f * acc[i][j];
                d2 = fmaxf(d2, 0.f);
                unsigned long long p =
                    ((unsigned long long)__float_as_uint(d2) << 32) | (unsigned)n;
                m = (p < m) ? p : m;   // equal d2 -> smaller n = numpy first-index
            }
        }
        qmin[tq * 8 + i][ts] = m;
    }
    __syncthreads();

    // ---- reduce over the 16 sample-groups, one atomic per query ----
    if (tid < BQ) {
        unsigned long long m = ~0ull;
#pragma unroll
        for (int j = 0; j < 16; ++j) {
            unsigned long long p = qmin[tid][j];
            m = (p < m) ? p : m;
        }
        atomicMin(&gmin[tid], m);
    }
}

// ---------------------------------------------------------------------------
// Kernel 3: unpack winner -> pred one-hot, imgs copy, l2s
// grid = B blocks x 256 threads
// ---------------------------------------------------------------------------
__global__ __launch_bounds__(256) void out_kernel(const float* __restrict__ s,
                                                  const int* __restrict__ classes,
                                                  const unsigned long long* __restrict__ gmin,
                                                  float* __restrict__ out,
                                                  int B_) {
    const int b = blockIdx.x;
    const int tid = threadIdx.x;
    const unsigned long long m = gmin[b];
    const unsigned idx = (unsigned)(m & 0xffffffffu);
    const float d2 = __uint_as_float((unsigned)(m >> 32));

    float* pred = out;                     // (B, NC)
    float* imgs = out + (size_t)B_ * NC;   // (B, D)
    float* l2s  = out + (size_t)B_ * NC + (size_t)B_ * D;  // (B,)

    if (tid < NC) {
        const int cls = classes[idx];
        pred[b * NC + tid] = (tid == cls) ? 1.f : 0.f;
    }
    if (tid == 0) l2s[b] = sqrtf(d2);

    const float4* src = (const float4*)(s + (size_t)idx * D);
    float4* dst = (float4*)(imgs + (size_t)b * D);
    for (int t = tid; t < D / 4; t += 256) dst[t] = src[t];
}

// ---------------------------------------------------------------------------
extern "C" void kernel_launch(void* const* d_in, const int* in_sizes, int n_in,
                              void* d_out, int out_size, void* d_ws, size_t ws_size,
                              hipStream_t stream) {
    const float* x       = (const float*)d_in[0];   // (B, D) fp32
    const float* s       = (const float*)d_in[1];   // (N, D) fp32
    const int*   classes = (const int*)d_in[2];     // (N,) int
    const int B_ = in_sizes[0] / D;                  // 128
    const int N  = in_sizes[2];                      // 50000

    // workspace layout: [0, B*8) packed u64 argmin ; [B*8, B*8+B*4) x2
    unsigned long long* gmin = (unsigned long long*)d_ws;
    float* x2g = (float*)((char*)d_ws + (size_t)B_ * sizeof(unsigned long long));

    init_kernel<<<B_, 64, 0, stream>>>(x, x2g, gmin);

    const int nblocks = (N + BS - 1) / BS;
    dist_kernel<<<nblocks, 256, 0, stream>>>(x, s, x2g, gmin, N);

    out_kernel<<<B_, 256, 0, stream>>>(s, classes, gmin, (float*)d_out, B_);
}